// Round 12
// baseline (361.799 us; speedup 1.0000x reference)
//
#include <hip/hip_runtime.h>

#define NDIM 128

typedef __attribute__((ext_vector_type(8))) short s16x8;
typedef __attribute__((ext_vector_type(8))) _Float16 h16x8;
typedef __attribute__((ext_vector_type(4))) float f32x4;

// fp32 <-> fp16 (RNE via hardware cvt)
__device__ __forceinline__ unsigned short f2h(float f) {
    _Float16 h = (_Float16)f;
    return *(unsigned short*)&h;
}
__device__ __forceinline__ float h2f(unsigned short u) {
    _Float16 h = *(_Float16*)&u;
    return (float)h;
}

// async global->LDS, 16 B per lane; lds dest is wave-uniform base
// (lane l lands at base + l*16). Source is per-lane (pre-swizzle there).
__device__ __forceinline__ void g2lds16(const void* g, void* l) {
    __builtin_amdgcn_global_load_lds(
        (const __attribute__((address_space(1))) void*)g,
        (__attribute__((address_space(3))) void*)l, 16, 0, 0);
}

// ---- zero deg + detect layout in ONE kernel (R11, proven-neutral) ----
__global__ __launch_bounds__(256) void init_detect_kernel(
    const int* __restrict__ raw, int* __restrict__ deg, int* __restrict__ flag,
    int E, int N) {
    const int tid = threadIdx.x;
    const int gtid = blockIdx.x * 256 + tid;
    const int gsz = gridDim.x * 256;
    for (int i = gtid; i < N; i += gsz) deg[i] = 0;
    if (blockIdx.x == 0) {
        __shared__ int any_nz;
        if (tid == 0) any_nz = 0;
        __syncthreads();
        int local = 0;
        const int samples = (E < 4096) ? E : 4096;
#pragma unroll
        for (int j = 0; j < 16; ++j) {
            int i = tid * 16 + j;
            if (i < samples) local |= raw[2 * i + 1];
        }
        if (local) atomicOr(&any_nz, 1);
        __syncthreads();
        if (tid == 0) *flag = any_nz;   // nonzero -> int32 layout
    }
}

// convert + fused degree histogram
__global__ void convert_kernel(const int* __restrict__ raw, const int* __restrict__ flag,
                               int* __restrict__ idx, int* __restrict__ deg, int E) {
    int i = blockIdx.x * 256 + threadIdx.x;
    if (i >= 2 * E) return;
    int v = (*flag == 0) ? raw[2 * i] : raw[i];
    idx[i] = v;
    if (i >= E) atomicAdd(&deg[v], 1);   // dst words
}

__global__ __launch_bounds__(256) void deg_reduce_kernel(
    const int* __restrict__ deg, int* __restrict__ partials, int n) {
    const int base = blockIdx.x * 1024;
    const int tid = threadIdx.x;
    int s = 0;
#pragma unroll
    for (int j = 0; j < 4; ++j) {
        int i = base + tid * 4 + j;
        if (i < n) s += deg[i];
    }
#pragma unroll
    for (int off = 32; off; off >>= 1) s += __shfl_down(s, off);
    __shared__ int ws[4];
    if ((tid & 63) == 0) ws[tid >> 6] = s;
    __syncthreads();
    if (tid == 0) partials[blockIdx.x] = ws[0] + ws[1] + ws[2] + ws[3];
}

__global__ void scan_partials_kernel(int* __restrict__ partials, int nb,
                                     int* __restrict__ row_start, int n) {
    __shared__ int sh[1024];
    const int tid = threadIdx.x;
    int v = (tid < nb) ? partials[tid] : 0;
    sh[tid] = v;
    __syncthreads();
    for (int off = 1; off < 1024; off <<= 1) {
        int a = sh[tid];
        int b = (tid >= off) ? sh[tid - off] : 0;
        __syncthreads();
        sh[tid] = a + b;
        __syncthreads();
    }
    if (tid < nb) partials[tid] = (tid == 0) ? 0 : sh[tid - 1];
    if (tid == 0) row_start[n] = sh[1023];
}

__global__ __launch_bounds__(256) void deg_downsweep_kernel(
    const int* __restrict__ deg, const int* __restrict__ partials,
    int* __restrict__ row_start, int* __restrict__ cursor,
    float* __restrict__ inv_deg, int n) {
    const int base = blockIdx.x * 1024;
    const int tid = threadIdx.x;
    const int i0 = base + tid * 4;
    int d[4];
    int s = 0;
#pragma unroll
    for (int j = 0; j < 4; ++j) {
        int i = i0 + j;
        d[j] = (i < n) ? deg[i] : 0;
        s += d[j];
    }
    const int lane = tid & 63;
    int incl = s;
#pragma unroll
    for (int off = 1; off < 64; off <<= 1) {
        int t = __shfl_up(incl, off);
        if (lane >= off) incl += t;
    }
    __shared__ int wsum[4];
    if (lane == 63) wsum[tid >> 6] = incl;
    __syncthreads();
    int woff = 0;
    const int w = tid >> 6;
    for (int k = 0; k < w; ++k) woff += wsum[k];
    int excl = incl - s + woff + partials[blockIdx.x];
#pragma unroll
    for (int j = 0; j < 4; ++j) {
        int i = i0 + j;
        if (i < n) {
            row_start[i] = excl;
            cursor[i] = excl;
            inv_deg[i] = 1.0f / (float)max(d[j], 1);
            excl += d[j];
        }
    }
}

// scatter v3: 8 edges/thread (8 independent atomic->store chains)
__global__ __launch_bounds__(256) void scatter_kernel(
    const int* __restrict__ idx, int* __restrict__ cursor,
    int* __restrict__ sorted_src, int E) {
    const int i0 = (blockIdx.x * 256 + threadIdx.x) * 8;
    if (i0 >= E) return;
    int s[8], d[8], p[8];
#pragma unroll
    for (int j = 0; j < 8; ++j) {
        if (i0 + j < E) {
            s[j] = idx[i0 + j];
            d[j] = idx[E + i0 + j];
        }
    }
#pragma unroll
    for (int j = 0; j < 8; ++j)
        if (i0 + j < E) p[j] = atomicAdd(&cursor[d[j]], 1);
#pragma unroll
    for (int j = 0; j < 8; ++j)
        if (i0 + j < E) sorted_src[p[j]] = s[j];
}

// ---- presplit W + split x0 in ONE kernel (index-split; R11) ----
// presplit v3 (items 0..327679): W -> B-frag order, fp16 hi + lo*2^11.
// wfrag[l][plane(4)][chunk(4)][ct(8)][lane(64)][j(8)], plane: 0=Wl-hi,
// 1=Wl-lo*2^11, 2=Wr-hi, 3=Wr-lo*2^11. Element (lane,j) of (ct,chunk):
// n = ct*16 + (lane&15), k = chunk*32 + (lane>>4)*8 + j  [B-frag, m89/m91].
__global__ __launch_bounds__(256) void prep_kernel(
    const float* __restrict__ Wl, const float* __restrict__ Wr,
    short* __restrict__ wfrag,
    const float* __restrict__ X, short* __restrict__ Xf16, int total4) {
    int t = blockIdx.x * 256 + threadIdx.x;
    if (t < 327680) {
        int j = t & 7;
        int lane = (t >> 3) & 63;
        int ct = (t >> 9) & 7;
        int chunk = (t >> 12) & 3;
        int plane = (t >> 14) & 3;
        int l = t >> 16;
        int nn = ct * 16 + (lane & 15);
        int k = chunk * 32 + (lane >> 4) * 8 + j;
        const float* src = (plane < 2) ? Wl : Wr;
        float v = src[(size_t)l * 16384 + (size_t)k * 128 + nn];
        unsigned short h = f2h(v);
        wfrag[t] = (plane & 1) ? (short)f2h((v - h2f(h)) * 2048.0f) : (short)h;
    } else {
        int i = t - 327680;
        if (i >= total4) return;
        float4 v = *(const float4*)(X + (size_t)i * 4);
        unsigned short f[4] = {f2h(v.x), f2h(v.y), f2h(v.z), f2h(v.w)};
        *(int2*)(Xf16 + (size_t)i * 4) = make_int2(
            (int)(f[0] | ((unsigned)f[1] << 16)), (int)(f[2] | ((unsigned)f[3] << 16)));
    }
}

// -------- mean aggregation v8 (R12: 16-lane groups, int4 loads) --------
// A/B vs v7: 4 nodes/wave (was 2), 16 B/lane/edge (was 8). Same load-
// instruction count per wave, 2x bytes per load -> 2x edge rate if the
// gather is load-issue-bound; unchanged if BW-bound. Avg deg 12 < 16 so
// the shorter edge slot rarely adds iterations.
__global__ __launch_bounds__(256) void aggregate_kernel(
    const short* __restrict__ Xf16, const int* __restrict__ row_start,
    const int* __restrict__ sorted_src, const float* __restrict__ inv_deg,
    short* __restrict__ Agf16, int n) {
    int gid = blockIdx.x * 256 + threadIdx.x;
    int node = gid >> 4;
    if (node >= n) return;
    const int lane16 = threadIdx.x & 15;
    const int q = lane16 << 3;          // 8 fp16 elements (16 B) per lane
    const int beg = row_start[node];
    const int end = row_start[node + 1];
    float acc[8] = {0.f, 0.f, 0.f, 0.f, 0.f, 0.f, 0.f, 0.f};
    for (int base = beg; base < end; base += 16) {
        const int cnt = min(end - base, 16);
        const int my_src = (lane16 < cnt) ? sorted_src[base + lane16] : 0;
        for (int jb = 0; jb < cnt; jb += 8) {
            int4 v[8];
            float m[8];
#pragma unroll
            for (int t = 0; t < 8; ++t) {
                const int j = jb + t;
                const int js = (j < cnt) ? j : (cnt - 1);
                const int s = __shfl(my_src, js, 16);
                v[t] = *(const int4*)(Xf16 + (size_t)s * 128 + q);
                m[t] = (j < cnt) ? 1.f : 0.f;
            }
#pragma unroll
            for (int t = 0; t < 8; ++t) {
                union { int4 i4; _Float16 h[8]; } u;
                u.i4 = v[t];
#pragma unroll
                for (int e = 0; e < 8; ++e)
                    acc[e] = fmaf(m[t], (float)u.h[e], acc[e]);
            }
        }
    }
    const float inv = inv_deg[node];
    unsigned short f[8];
#pragma unroll
    for (int e = 0; e < 8; ++e) f[e] = f2h(acc[e] * inv);
    *(int4*)(Agf16 + (size_t)node * 128 + q) = make_int4(
        (int)(f[0] | ((unsigned)f[1] << 16)), (int)(f[2] | ((unsigned)f[3] << 16)),
        (int)(f[4] | ((unsigned)f[5] << 16)), (int)(f[6] | ((unsigned)f[7] << 16)));
}

// ------- GEMM v15 (R12: BM=32 for latency hiding; fp16 pipeline) -------
// v14 was latency-bound: 782 blocks = 3/CU with 4 barrier-drain serials per
// block. BM=32: 1563 blocks (6.1/CU), LDS 8 KB, 64 MFMAs/wave. Each of the
// 4 waves owns all 32 rows x a 32-col tile (acc[2][2], ctbase=wave*2). W
// re-read doubles (128 KB x 1563 = 200 MB L2-hit, ~+3 us distributed).
// Staging flow unchanged (g2lds + involution swizzle, rule #21):
// per kp-half, plane = wave>>1, rhalf = (wave&1)*16, 2 issues x 1 KB.
__global__ __launch_bounds__(256, 4) void gemm_kernel(
    const short* __restrict__ Agf16, const short* __restrict__ Xf16,
    const short* __restrict__ wfrag,   // this layer's 65536-elem block
    const float* __restrict__ bias,
    float* __restrict__ Yf, short* __restrict__ Yf16,
    int n, int do_relu) {
    __shared__ __align__(16) short sT[2][32][64];   // 8 KB: Ag, X fp16 half-rows
    const int tid = threadIdx.x;
    const int lane = tid & 63;
    const int wave = tid >> 6;
    const int ln15 = lane & 15;
    const int quad = lane >> 4;
    const int row0 = blockIdx.x * 32;
    const int wc0 = wave * 32;       // wave's col offset
    const int ctbase = wave * 2;     // global col-tile base

    f32x4 accM[2][2], accR[2][2];
#pragma unroll
    for (int i = 0; i < 2; ++i)
#pragma unroll
        for (int j = 0; j < 2; ++j) { accM[i][j] = (f32x4)(0.f); accR[i][j] = (f32x4)(0.f); }

    // staging: plane = wave>>1 (0=Ag, 1=X); wave&1 -> 16-row half.
    // Per issue: 8 rows x 128 B = 1 KB; lane l -> row rbase+(l>>3),
    // slot c=l&7; source slot = c ^ (rl&7)  [involution].
    const short* pbase = (wave < 2) ? Agf16 : Xf16;
    const int rhalf = (wave & 1) * 16;
    const int rl = lane >> 3;                // row within 8-row group
    const int gslot = (lane & 7) ^ rl;       // pre-swizzled source slot

    for (int kp = 0; kp < 2; ++kp) {
        __syncthreads();   // prior half's ds_reads complete before overwrite
#pragma unroll
        for (int i = 0; i < 2; ++i) {
            const int rloc = rhalf + i * 8;
            int grow = row0 + rloc + rl;
            if (grow >= n) grow = n - 1;
            const short* g = pbase + (size_t)grow * 128 + kp * 64 + gslot * 8;
            g2lds16(g, &sT[wave >> 1][rloc][0]);
        }
        __syncthreads();   // drains vmcnt(0): staging visible to all waves

#pragma unroll
        for (int ch = 0; ch < 2; ++ch) {
            const int chunk = kp * 2 + ch;
            h16x8 fAg[2], fX[2];
#pragma unroll
            for (int rt = 0; rt < 2; ++rt) {
                const int r = rt * 16 + ln15;
                const int cc = (ch * 4 + quad) ^ (r & 7);
                fAg[rt] = *(const h16x8*)&sT[0][r][cc * 8];
                fX[rt]  = *(const h16x8*)&sT[1][r][cc * 8];
            }
#pragma unroll
            for (int ct = 0; ct < 2; ++ct) {
                const short* wb = wfrag + (chunk << 12) + ((ctbase + ct) << 9) + (lane << 3);
                const h16x8 wlh = *(const h16x8*)(wb);            // Wl-hi
                const h16x8 wll = *(const h16x8*)(wb + 16384);    // Wl-lo*2^11
                const h16x8 wrh = *(const h16x8*)(wb + 32768);    // Wr-hi
                const h16x8 wrl = *(const h16x8*)(wb + 49152);    // Wr-lo*2^11
#pragma unroll
                for (int rt = 0; rt < 2; ++rt) {
                    accM[rt][ct] = __builtin_amdgcn_mfma_f32_16x16x32_f16(fAg[rt], wlh, accM[rt][ct], 0, 0, 0);
                    accR[rt][ct] = __builtin_amdgcn_mfma_f32_16x16x32_f16(fAg[rt], wll, accR[rt][ct], 0, 0, 0);
                    accM[rt][ct] = __builtin_amdgcn_mfma_f32_16x16x32_f16(fX[rt],  wrh, accM[rt][ct], 0, 0, 0);
                    accR[rt][ct] = __builtin_amdgcn_mfma_f32_16x16x32_f16(fX[rt],  wrl, accR[rt][ct], 0, 0, 0);
                }
            }
        }
    }

    // epilogue: C/D layout col=lane&15, row=quad*4+reg [m89]
#pragma unroll
    for (int rt = 0; rt < 2; ++rt) {
#pragma unroll
        for (int ct = 0; ct < 2; ++ct) {
            const int col = wc0 + ct * 16 + ln15;
            const float bv = bias[col];
#pragma unroll
            for (int r = 0; r < 4; ++r) {
                const int grow = row0 + rt * 16 + quad * 4 + r;
                if (grow < n) {
                    float v = accM[rt][ct][r] + accR[rt][ct][r] * 4.8828125e-4f + bv;
                    if (do_relu) v = fmaxf(v, 0.f);
                    if (Yf) {
                        Yf[(size_t)grow * NDIM + col] = v;
                    } else {
                        Yf16[(size_t)grow * 128 + col] = (short)f2h(v);
                    }
                }
            }
        }
    }
}

// ---------------- host launcher ----------------
extern "C" void kernel_launch(void* const* d_in, const int* in_sizes, int n_in,
                              void* d_out, int out_size, void* d_ws, size_t ws_size,
                              hipStream_t stream) {
    const float* x0   = (const float*)d_in[0];
    const int*   eraw = (const int*)d_in[1];
    const float* Wl   = (const float*)d_in[2];
    const float* bl   = (const float*)d_in[3];
    const float* Wr   = (const float*)d_in[4];
    float* out = (float*)d_out;

    const int N = in_sizes[0] / NDIM;   // 50000
    const int E = in_sizes[1] / 2;      // 600000

    auto align_up = [](size_t v) { return (v + 255) & ~(size_t)255; };
    char* p = (char*)d_ws;
    int* idx = (int*)p;                 p += align_up((size_t)2 * E * 4);
    int* deg = (int*)p;                 p += align_up((size_t)(N + 1) * 4);
    int* flag = deg + N;
    int* row_start = (int*)p;           p += align_up((size_t)(N + 1) * 4);
    int* cursor = (int*)p;              p += align_up((size_t)N * 4);
    int* ssrc = (int*)p;                p += align_up((size_t)E * 4);
    float* invd = (float*)p;            p += align_up((size_t)N * 4);
    int* partials = (int*)p;            p += align_up((size_t)1024 * 4);
    short* wfrag = (short*)p;           p += align_up((size_t)327680 * 2);
    // 3 rotating fp16 activation planes [node][128]
    short* f16[3];
    for (int s = 0; s < 3; ++s) {
        f16[s] = (short*)p;             p += align_up((size_t)N * 128 * 2);
    }

    const int nb = (N + 1023) / 1024;
    const int preptotal = 327680 + N * 32;

    init_detect_kernel<<<256, 256, 0, stream>>>(eraw, deg, flag, E, N);
    convert_kernel<<<(2 * E + 255) / 256, 256, 0, stream>>>(eraw, flag, idx, deg, E);
    deg_reduce_kernel<<<nb, 256, 0, stream>>>(deg, partials, N);
    scan_partials_kernel<<<1, 1024, 0, stream>>>(partials, nb, row_start, N);
    deg_downsweep_kernel<<<nb, 256, 0, stream>>>(deg, partials, row_start, cursor, invd, N);
    scatter_kernel<<<(E + 2047) / 2048, 256, 0, stream>>>(idx, cursor, ssrc, E);
    prep_kernel<<<(preptotal + 255) / 256, 256, 0, stream>>>(
        Wl, Wr, wfrag, x0, f16[0], N * 32);

    // slot rotation per layer: X=xs, AG=(xs+1)%3, Y=(xs+2)%3 (all distinct)
    int xs = 0;
    for (int l = 0; l < 5; ++l) {
        const int as_ = (xs + 1) % 3;
        const int ys = (xs + 2) % 3;
        aggregate_kernel<<<(N * 16 + 255) / 256, 256, 0, stream>>>(
            f16[xs], row_start, ssrc, invd, f16[as_], N);
        if (l < 4) {
            gemm_kernel<<<(N + 31) / 32, 256, 0, stream>>>(
                f16[as_], f16[xs], wfrag + (size_t)l * 65536,
                bl + (size_t)l * NDIM, nullptr, f16[ys], N, 1);
        } else {
            gemm_kernel<<<(N + 31) / 32, 256, 0, stream>>>(
                f16[as_], f16[xs], wfrag + (size_t)l * 65536,
                bl + (size_t)l * NDIM, out, nullptr, N, 0);
        }
        xs = ys;
    }
}